// Round 12
// baseline (1060.628 us; speedup 1.0000x reference)
//
#include <hip/hip_runtime.h>
#include <cstdint>
#include <cstddef>

// ---------------------------------------------------------------------------
// QLoRABigNet: 6 blocks x (linear, relu, linear, relu, linear) + LayerNorm.
// D=1024, BATCH=16384. 18 bf16 MFMA GEMMs, LoRA merged into dequantized W.
//
// R16: INTERIOR LAYERNORM FUSED INTO GEMMs (blocks 0-4 boundaries).
//   LN is affine/row: y=(h-mu)*rs*g+beta. Fold gamma into W of the NEXT
//   block's first linear (dequant: W' = g (.) (W+BA), u[n]=rowsum(W'),
//   vb[n]=beta.W_orig[n]). GEMM3 (MODE 3) accumulates per-row (sum,sumsq)
//   of its fp32 outputs via quad-shuffle + 2 atomicAdd/row. Next GEMM1
//   (MODE 4) applies o = rs*(acc - mu*u[n]) + vb[n] + bias[n], relu, in its
//   epilogue. The 5 interior ln_bf16 dispatches (67 MB, ~11us each) vanish.
//   Stats (5x16384x2 f32) live at the ws tail (ws ~288 MB per reset fill);
//   host-side guard falls back to the unfused path if ws_size is small.
//   Block 5 final LN unchanged (exact fp32 out).
// R13/R14 (880.3us best): 128^2 SWAP=0 GEMM, lora precompute, bf16 pre-LN.
// Cross-container clock spread is +-3-5% on totals (R13=880 vs R15=942 with
// fillBuffer 6652-6789 vs 6588-6652 GB/s) — per-dispatch counters are the
// cross-run currency.
// CLOSED: 256^2 pipelines, frag-lead, reg-streaming, wide tile, SWAP=1.
// ---------------------------------------------------------------------------

typedef short  bf16x8 __attribute__((ext_vector_type(8)));   // 8 bf16 (4 VGPRs)
typedef float  f32x4  __attribute__((ext_vector_type(4)));

__device__ __forceinline__ unsigned short f2bf(float f) {
  unsigned int u = __builtin_bit_cast(unsigned int, f);
  u += 0x7FFFu + ((u >> 16) & 1u);
  return (unsigned short)(u >> 16);
}

__device__ __forceinline__ void async_copy16(void* lds, const void* g) {
  __builtin_amdgcn_global_load_lds(
      (const __attribute__((address_space(1))) void*)(uintptr_t)(g),
      (__attribute__((address_space(3))) void*)(unsigned int)(uintptr_t)(lds),
      16, 0, 0);
}

// ---------------------------------------------------------------------------
// Zero the 5 stats buffers (atomically accumulated each launch).
// grid 160, block 256: 160*256*4 = 163840 floats = 5*16384*2.
// ---------------------------------------------------------------------------
__global__ __launch_bounds__(256) void zero_stats_kernel(float* st) {
  const size_t i = (size_t)blockIdx.x * 256 + threadIdx.x;
  *(float4*)(st + i * 4) = make_float4(0.f, 0.f, 0.f, 0.f);
}

// ---------------------------------------------------------------------------
// LoRA precompute: LA[slot][o][i] = sum_r lora_b[slot][o][r]*lora_a[slot][r][i]
// grid (256, 3), block 256.
// ---------------------------------------------------------------------------
__global__ __launch_bounds__(256) void lora_kernel(
    const float* __restrict__ lora_a,    // [3][32][1024]
    const float* __restrict__ lora_b,    // [3][1024][32]
    float* __restrict__ LA) {            // [3][1024][1024]
  const int slot = blockIdx.y;
  const int o0   = blockIdx.x * 4;
  const int t    = threadIdx.x;
  const float* A = lora_a + slot * 32768 + t * 4;
  const float* B = lora_b + slot * 32768 + o0 * 32;

  float acc[4][4];
#pragma unroll
  for (int k = 0; k < 4; ++k)
#pragma unroll
    for (int j = 0; j < 4; ++j) acc[k][j] = 0.f;

#pragma unroll 8
  for (int r = 0; r < 32; ++r) {
    const float4 a4 = *(const float4*)(A + r * 1024);
#pragma unroll
    for (int k = 0; k < 4; ++k) {
      const float br = B[k * 32 + r];
      acc[k][0] = fmaf(br, a4.x, acc[k][0]);
      acc[k][1] = fmaf(br, a4.y, acc[k][1]);
      acc[k][2] = fmaf(br, a4.z, acc[k][2]);
      acc[k][3] = fmaf(br, a4.w, acc[k][3]);
    }
  }
#pragma unroll
  for (int k = 0; k < 4; ++k) {
    float4 o = make_float4(acc[k][0], acc[k][1], acc[k][2], acc[k][3]);
    *(float4*)(LA + (size_t)slot * 1048576 + (size_t)(o0 + k) * 1024 + t * 4) = o;
  }
}

// ---------------------------------------------------------------------------
// Dequant (+ LoRA add, + optional gamma-fold for layers 3,6,9,12,15 when
// fold=1: W' = g(.)W, u[row]=rowsum(bf16 W'), vb[row]=beta.W_orig[row]).
// Block covers rows blk*4..+3, thread t covers cols t*4..+3 for each row.
// grid (256, 18), block 256.
// ---------------------------------------------------------------------------
__global__ __launch_bounds__(256) void dequant_kernel(
    const int* __restrict__ wq, const float* __restrict__ wn,
    const float* __restrict__ LA,        // [3][1024][1024] fp32 (B@A)
    const float* __restrict__ lnw, const float* __restrict__ lnb,
    unsigned short* __restrict__ Wbf,
    float* __restrict__ ubuf,            // [5][1024]
    float* __restrict__ vbuf,            // [5][1024]
    int fold) {
  __shared__ float red[4][4][2];
  const int l   = blockIdx.y;
  const int t   = threadIdx.x;
  const int blk = blockIdx.x;
  const long base = (long)l * 1048576;
  const float s = 2.0f / 15.0f;

  const int slot = (l == 0) ? 0 : (l == 6) ? 1 : (l == 12) ? 2 : -1;
  const int fs = (fold && l > 0 && (l % 3) == 0) ? (l / 3 - 1) : -1;

  int4  q[4];
  float nrm[4];
  float4 c4[4];
#pragma unroll
  for (int k = 0; k < 4; ++k) {
    const int i4 = blk * 1024 + k * 256 + t;
    q[k]   = *(const int4*)(wq + base + (long)i4 * 4);
    nrm[k] = wn[l * 65536 + (i4 >> 2)];
  }
  if (slot >= 0) {
    const float* LAp = LA + (size_t)slot * 1048576;
#pragma unroll
    for (int k = 0; k < 4; ++k) {
      const int i4 = blk * 1024 + k * 256 + t;
      c4[k] = *(const float4*)(LAp + (size_t)i4 * 4);
    }
  }

  float v[4][4];
#pragma unroll
  for (int k = 0; k < 4; ++k) {
    v[k][0] = ((float)q[k].x * s - 1.0f) * nrm[k];
    v[k][1] = ((float)q[k].y * s - 1.0f) * nrm[k];
    v[k][2] = ((float)q[k].z * s - 1.0f) * nrm[k];
    v[k][3] = ((float)q[k].w * s - 1.0f) * nrm[k];
  }
  if (slot >= 0) {
#pragma unroll
    for (int k = 0; k < 4; ++k) {
      v[k][0] += c4[k].x; v[k][1] += c4[k].y;
      v[k][2] += c4[k].z; v[k][3] += c4[k].w;
    }
  }

  float4 g4 = make_float4(1.f, 1.f, 1.f, 1.f);
  float4 b4 = make_float4(0.f, 0.f, 0.f, 0.f);
  if (fs >= 0) {
    g4 = *(const float4*)(lnw + fs * 1024 + t * 4);
    b4 = *(const float4*)(lnb + fs * 1024 + t * 4);
  }

  float us[4] = {0.f, 0.f, 0.f, 0.f}, vbs[4] = {0.f, 0.f, 0.f, 0.f};
#pragma unroll
  for (int k = 0; k < 4; ++k) {
    if (fs >= 0) {
      vbs[k] = b4.x * v[k][0] + b4.y * v[k][1] +
               b4.z * v[k][2] + b4.w * v[k][3];
      v[k][0] *= g4.x; v[k][1] *= g4.y; v[k][2] *= g4.z; v[k][3] *= g4.w;
    }
    unsigned short u[4] = {f2bf(v[k][0]), f2bf(v[k][1]),
                           f2bf(v[k][2]), f2bf(v[k][3])};
    const long e0 = base + ((long)blk * 1024 + k * 256 + t) * 4;
    *(uint2*)(Wbf + e0) = *(uint2*)u;
    if (fs >= 0) {
      us[k] = __builtin_bit_cast(float, (unsigned)u[0] << 16) +
              __builtin_bit_cast(float, (unsigned)u[1] << 16) +
              __builtin_bit_cast(float, (unsigned)u[2] << 16) +
              __builtin_bit_cast(float, (unsigned)u[3] << 16);
    }
  }

  if (fs >= 0) {
    const int wv = t >> 6, lnn = t & 63;
#pragma unroll
    for (int k = 0; k < 4; ++k) {
      float a = us[k], c = vbs[k];
#pragma unroll
      for (int off = 32; off; off >>= 1) {
        a += __shfl_xor(a, off);
        c += __shfl_xor(c, off);
      }
      if (lnn == 0) { red[wv][k][0] = a; red[wv][k][1] = c; }
    }
    __syncthreads();
    if (t < 4) {
      const float a = red[0][t][0] + red[1][t][0] + red[2][t][0] + red[3][t][0];
      const float c = red[0][t][1] + red[1][t][1] + red[2][t][1] + red[3][t][1];
      ubuf[fs * 1024 + blk * 4 + t] = a;
      vbuf[fs * 1024 + blk * 4 + t] = c;
    }
  }
}

// ---------------------------------------------------------------------------
// fp32 -> bf16 for the initial x. grid 4096, block 256 (16 elems/thread).
// ---------------------------------------------------------------------------
__global__ __launch_bounds__(256) void cvt_bf16_kernel(
    const float* __restrict__ in, unsigned short* __restrict__ out) {
  const long b0 = (long)blockIdx.x * 4096 + threadIdx.x * 4;
  float4 v[4];
#pragma unroll
  for (int k = 0; k < 4; ++k) v[k] = *(const float4*)(in + b0 + k * 1024);
#pragma unroll
  for (int k = 0; k < 4; ++k) {
    unsigned short u[4] = {f2bf(v[k].x), f2bf(v[k].y), f2bf(v[k].z), f2bf(v[k].w)};
    *(ushort4*)(out + b0 + k * 1024) = *(ushort4*)u;
  }
}

// ---------------------------------------------------------------------------
// GEMM (proven 128^2 structure): out[m][n] = sum_k H[m][k]*W[n][k] + bias[n].
// 128x128 tile, BK=64, 4 waves, 4 blocks/CU, grid 1024, block 256.
// C/D: col=lane&15 (n), row=quad*4+reg (m); scalar epilogue.
// MODE 0: relu, bf16.  MODE 2: bf16 (no relu).
// MODE 3: bf16 (no relu) + per-row (sum,sumsq) atomics into st.
// MODE 4: fused-LN apply (st,uv,vb) + relu, bf16.
// ---------------------------------------------------------------------------
template <int MODE>
__global__ __launch_bounds__(256, 4) void gemm_kernel(
    const unsigned short* __restrict__ H,
    const unsigned short* __restrict__ W,
    const float* __restrict__ bias,
    unsigned short* __restrict__ outb,
    float* __restrict__ st,
    const float* __restrict__ uv,
    const float* __restrict__ vb) {
  constexpr int K = 1024;
  constexpr int NN = 1024;

  __shared__ uint4 ldsq[2048];              // 32 KiB
  char* base = (char*)ldsq;

  const int tid = threadIdx.x;
  const int w   = tid >> 6;
  const int ln  = tid & 63;
  const int b   = blockIdx.x;
  const int m0  = ((b & 7) * 16 + (b >> 6)) * 128;
  const int n0  = ((b >> 3) & 7) * 128;

  const int gc = (ln & 7) ^ (ln >> 3);
  const unsigned short* gA = H + (size_t)(m0 + w * 32 + (ln >> 3)) * K + gc * 8;
  const unsigned short* gB = W + (size_t)(n0 + w * 32 + (ln >> 3)) * K + gc * 8;
  char* ldsA = base + w * 4096;
  char* ldsB = base + 16384 + w * 4096;

  const int quad = ln >> 4;
  const int lrow = ln & 15;
  const int sw   = lrow & 7;
  const int c0   = ((quad)     ^ sw) * 16;
  const int c1   = ((quad + 4) ^ sw) * 16;
  const int wm   = (w >> 1) * 64;
  const int wn   = (w & 1) * 64;
  const char* fragA = base + (wm + lrow) * 128;
  const char* fragB = base + 16384 + (wn + lrow) * 128;

  f32x4 acc[4][4];
#pragma unroll
  for (int i = 0; i < 4; ++i)
#pragma unroll
    for (int j = 0; j < 4; ++j) acc[i][j] = (f32x4){0.f, 0.f, 0.f, 0.f};

  for (int kt = 0; kt < 16; ++kt) {
    const unsigned short* pA = gA + kt * 64;
    const unsigned short* pB = gB + kt * 64;
#pragma unroll
    for (int i = 0; i < 4; ++i) {
      async_copy16(ldsA + i * 1024, pA + (size_t)i * 8 * K);
      async_copy16(ldsB + i * 1024, pB + (size_t)i * 8 * K);
    }
    __syncthreads();
#pragma unroll
    for (int kk = 0; kk < 2; ++kk) {
      const int co = kk ? c1 : c0;
      bf16x8 af[4], bg[4];
#pragma unroll
      for (int mt = 0; mt < 4; ++mt)
        af[mt] = *(const bf16x8*)(fragA + mt * 2048 + co);
#pragma unroll
      for (int nt = 0; nt < 4; ++nt)
        bg[nt] = *(const bf16x8*)(fragB + nt * 2048 + co);
#pragma unroll
      for (int mt = 0; mt < 4; ++mt)
#pragma unroll
        for (int nt = 0; nt < 4; ++nt)
          acc[mt][nt] = __builtin_amdgcn_mfma_f32_16x16x32_bf16(
              af[mt], bg[nt], acc[mt][nt], 0, 0, 0);
    }
    __syncthreads();
  }

  if (MODE == 4) {
    // fused-LN apply: o = rs[m]*(acc - mu[m]*u[n]) + vb[n] + bias[n], relu
    float mu[4][4], rs[4][4];
#pragma unroll
    for (int mt = 0; mt < 4; ++mt) {
      const int mb = m0 + wm + mt * 16 + quad * 4;
      const float4 s01 = *(const float4*)(st + (size_t)mb * 2);
      const float4 s23 = *(const float4*)(st + (size_t)mb * 2 + 4);
      const float S[4] = {s01.x, s01.z, s23.x, s23.z};
      const float Q[4] = {s01.y, s01.w, s23.y, s23.w};
#pragma unroll
      for (int r = 0; r < 4; ++r) {
        const float m_ = S[r] * (1.0f / 1024.0f);
        const float var = Q[r] * (1.0f / 1024.0f) - m_ * m_;
        mu[mt][r] = m_;
        rs[mt][r] = rsqrtf(var + 1e-5f);
      }
    }
#pragma unroll
    for (int nt = 0; nt < 4; ++nt) {
      const int n = n0 + wn + nt * 16 + lrow;
      const float un = uv[n];
      const float bs = vb[n] + bias[n];
#pragma unroll
      for (int mt = 0; mt < 4; ++mt) {
        const int mb = m0 + wm + mt * 16 + quad * 4;
        const f32x4 v = acc[mt][nt];
#pragma unroll
        for (int r = 0; r < 4; ++r) {
          float o = rs[mt][r] * (v[r] - mu[mt][r] * un) + bs;
          o = fmaxf(o, 0.0f);
          outb[(size_t)(mb + r) * NN + n] = f2bf(o);
        }
      }
    }
  } else {
    float ss[4][4], qq[4][4];
    if (MODE == 3) {
#pragma unroll
      for (int i = 0; i < 4; ++i)
#pragma unroll
        for (int j = 0; j < 4; ++j) { ss[i][j] = 0.f; qq[i][j] = 0.f; }
    }
#pragma unroll
    for (int nt = 0; nt < 4; ++nt) {
      const int n = n0 + wn + nt * 16 + lrow;
      const float bs = bias[n];
#pragma unroll
      for (int mt = 0; mt < 4; ++mt) {
        const int mb = m0 + wm + mt * 16 + quad * 4;
        const f32x4 v = acc[mt][nt];
#pragma unroll
        for (int r = 0; r < 4; ++r) {
          float o = v[r] + bs;
          if (MODE == 0) o = fmaxf(o, 0.0f);
          outb[(size_t)(mb + r) * NN + n] = f2bf(o);
          if (MODE == 3) { ss[mt][r] += o; qq[mt][r] += o * o; }
        }
      }
    }
    if (MODE == 3) {
      // reduce each row's 64-col partial over the quad's 16 lanes
#pragma unroll
      for (int mt = 0; mt < 4; ++mt)
#pragma unroll
        for (int r = 0; r < 4; ++r) {
          float s = ss[mt][r], q = qq[mt][r];
#pragma unroll
          for (int off = 1; off < 16; off <<= 1) {
            s += __shfl_xor(s, off);
            q += __shfl_xor(q, off);
          }
          if (lrow == 0) {
            const int row = m0 + wm + mt * 16 + quad * 4 + r;
            atomicAdd(st + (size_t)row * 2,     s);
            atomicAdd(st + (size_t)row * 2 + 1, q);
          }
        }
    }
  }
}

// ---------------------------------------------------------------------------
// LayerNorm, bf16 in -> bf16 hA and/or fp32 out. One WAVE per row; lane owns
// cols [ln*16, ln*16+16). grid 4096, block 256.
// ---------------------------------------------------------------------------
__global__ __launch_bounds__(256) void ln_bf16_kernel(
    const unsigned short* __restrict__ in, const float* __restrict__ lnw,
    const float* __restrict__ lnb, unsigned short* __restrict__ outb,
    float* __restrict__ outf, int wbf, int wf32) {
  const int wv = threadIdx.x >> 6;
  const int ln = threadIdx.x & 63;
  const int row = blockIdx.x * 4 + wv;
  const unsigned short* p = in + (size_t)row * 1024 + ln * 16;

  const uint4 r0 = *(const uint4*)(p);
  const uint4 r1 = *(const uint4*)(p + 8);
  const unsigned ru[8] = {r0.x, r0.y, r0.z, r0.w, r1.x, r1.y, r1.z, r1.w};

  float f[16];
#pragma unroll
  for (int i = 0; i < 8; ++i) {
    f[2 * i]     = __builtin_bit_cast(float, ru[i] << 16);
    f[2 * i + 1] = __builtin_bit_cast(float, ru[i] & 0xffff0000u);
  }

  float s = 0.f, q = 0.f;
#pragma unroll
  for (int i = 0; i < 16; ++i) { s += f[i]; q += f[i] * f[i]; }
#pragma unroll
  for (int off = 32; off; off >>= 1) {
    s += __shfl_xor(s, off);
    q += __shfl_xor(q, off);
  }
  const float mu  = s * (1.0f / 1024.0f);
  const float var = q * (1.0f / 1024.0f) - mu * mu;
  const float rs  = rsqrtf(var + 1e-5f);

  const float* wp = lnw + ln * 16;
  const float* bp = lnb + ln * 16;
  float y[16];
#pragma unroll
  for (int i = 0; i < 16; ++i) y[i] = (f[i] - mu) * rs * wp[i] + bp[i];

  if (wbf) {
    unsigned o[8];
#pragma unroll
    for (int i = 0; i < 8; ++i)
      o[i] = (unsigned)f2bf(y[2 * i]) | ((unsigned)f2bf(y[2 * i + 1]) << 16);
    unsigned short* dst = outb + (size_t)row * 1024 + ln * 16;
    *(uint4*)(dst)     = make_uint4(o[0], o[1], o[2], o[3]);
    *(uint4*)(dst + 8) = make_uint4(o[4], o[5], o[6], o[7]);
  }
  if (wf32) {
    float* dst = outf + (size_t)row * 1024 + ln * 16;
#pragma unroll
    for (int c = 0; c < 4; ++c)
      *(float4*)(dst + c * 4) = make_float4(y[c * 4], y[c * 4 + 1],
                                            y[c * 4 + 2], y[c * 4 + 3]);
  }
}

// ---------------------------------------------------------------------------
extern "C" void kernel_launch(void* const* d_in, const int* in_sizes, int n_in,
                              void* d_out, int out_size, void* d_ws, size_t ws_size,
                              hipStream_t stream) {
  const float* x    = (const float*)d_in[0];
  const int*   wq   = (const int*)d_in[1];
  const float* wn   = (const float*)d_in[2];
  const float* bias = (const float*)d_in[3];
  const float* la   = (const float*)d_in[4];
  const float* lb   = (const float*)d_in[5];
  const float* lnw  = (const float*)d_in[6];
  const float* lnb  = (const float*)d_in[7];
  float* out = (float*)d_out;

  char* ws = (char*)d_ws;
  unsigned short* Wbf = (unsigned short*)ws;                         // 37.75 MB
  unsigned short* hA  = (unsigned short*)(ws + 37748736);            // 32 MB
  unsigned short* hB  = (unsigned short*)(ws + 37748736 + 33554432); // 32 MB
  float* LA = (float*)hB;   // 12 MB, consumed by dequant before hB is written

  // stats/u/vb at workspace tail (reset fill shows ws ~288 MB); fall back to
  // the unfused path if the workspace is too small.
  const size_t tail = (size_t)5 * 16384 * 2 * 4 + (size_t)2 * 5 * 1024 * 4;
  const bool fused = ws_size >= 104857600ull + tail + 4096;
  float* stats = nullptr; float* ubuf = nullptr; float* vbuf = nullptr;
  if (fused) {
    char* tp = ws + ((ws_size - tail) & ~(size_t)255);
    stats = (float*)tp;                  // [5][16384][2]
    ubuf  = stats + (size_t)5 * 16384 * 2;
    vbuf  = ubuf + 5 * 1024;
  }

  if (fused) zero_stats_kernel<<<160, 256, 0, stream>>>(stats);
  lora_kernel<<<dim3(256, 3), 256, 0, stream>>>(la, lb, LA);
  dequant_kernel<<<dim3(256, 18), 256, 0, stream>>>(
      wq, wn, LA, lnw, lnb, Wbf, ubuf, vbuf, fused ? 1 : 0);
  cvt_bf16_kernel<<<4096, 256, 0, stream>>>(x, hA);

#define WL(i) (Wbf + (size_t)(i) * 1048576)
  if (fused) {
    // block 0
    gemm_kernel<0><<<1024, 256, 0, stream>>>(hA, WL(0), bias, hB,
                                             nullptr, nullptr, nullptr);
    gemm_kernel<0><<<1024, 256, 0, stream>>>(hB, WL(1), bias + 1024, hA,
                                             nullptr, nullptr, nullptr);
    gemm_kernel<3><<<1024, 256, 0, stream>>>(hA, WL(2), bias + 2048, hB,
                                             stats, nullptr, nullptr);
    // blocks 1..4: G1 fused (stats blk-1), G3 accumulates stats blk
    for (int blk = 1; blk <= 4; ++blk) {
      const int l = blk * 3;
      unsigned short* in  = (blk & 1) ? hB : hA;
      unsigned short* mid = (blk & 1) ? hA : hB;
      gemm_kernel<4><<<1024, 256, 0, stream>>>(
          in, WL(l), bias + l * 1024, mid,
          stats + (size_t)(blk - 1) * 32768,
          ubuf + (blk - 1) * 1024, vbuf + (blk - 1) * 1024);
      gemm_kernel<0><<<1024, 256, 0, stream>>>(
          mid, WL(l + 1), bias + (l + 1) * 1024, in,
          nullptr, nullptr, nullptr);
      gemm_kernel<3><<<1024, 256, 0, stream>>>(
          in, WL(l + 2), bias + (l + 2) * 1024, mid,
          stats + (size_t)blk * 32768, nullptr, nullptr);
    }
    // block 5: fused G1 (stats 4), plain G2/G3, exact final LN -> fp32 out
    gemm_kernel<4><<<1024, 256, 0, stream>>>(
        hB, WL(15), bias + 15 * 1024, hA,
        stats + (size_t)4 * 32768, ubuf + 4 * 1024, vbuf + 4 * 1024);
    gemm_kernel<0><<<1024, 256, 0, stream>>>(hA, WL(16), bias + 16 * 1024, hB,
                                             nullptr, nullptr, nullptr);
    gemm_kernel<2><<<1024, 256, 0, stream>>>(hB, WL(17), bias + 17 * 1024, hA,
                                             nullptr, nullptr, nullptr);
    ln_bf16_kernel<<<4096, 256, 0, stream>>>(
        hA, lnw + 5 * 1024, lnb + 5 * 1024, nullptr, out, 0, 1);
  } else {
    // fallback: R13/R14 unfused path
    for (int blk = 0; blk < 6; ++blk) {
      const int l = blk * 3;
      gemm_kernel<0><<<1024, 256, 0, stream>>>(hA, WL(l), bias + l * 1024, hB,
                                               nullptr, nullptr, nullptr);
      gemm_kernel<0><<<1024, 256, 0, stream>>>(hB, WL(l + 1),
                                               bias + (l + 1) * 1024, hA,
                                               nullptr, nullptr, nullptr);
      gemm_kernel<2><<<1024, 256, 0, stream>>>(hA, WL(l + 2),
                                               bias + (l + 2) * 1024, hB,
                                               nullptr, nullptr, nullptr);
      if (blk < 5) {
        ln_bf16_kernel<<<4096, 256, 0, stream>>>(
            hB, lnw + blk * 1024, lnb + blk * 1024, hA, nullptr, 1, 0);
      } else {
        ln_bf16_kernel<<<4096, 256, 0, stream>>>(
            hB, lnw + blk * 1024, lnb + blk * 1024, nullptr, out, 0, 1);
      }
    }
  }
#undef WL
}

// Round 13
// 946.041 us; speedup vs baseline: 1.1211x; 1.1211x over previous
//
#include <hip/hip_runtime.h>
#include <cstdint>
#include <cstddef>

// ---------------------------------------------------------------------------
// QLoRABigNet: 6 blocks x (linear, relu, linear, relu, linear) + LayerNorm.
// D=1024, BATCH=16384. 18 bf16 MFMA GEMMs, LoRA merged into dequantized W.
//
// R17 = revert to R14/R15 (best-known consolidated config) after R16's
// LN-fusion regressed (fused GEMM rows 72us vs 44: MODE3 stats atomics +
// MODE4 apply fatten the epilogue beyond the 11us LN they replace).
// Third confirmation that this structure's epilogue is latency-critical:
// SWAP=1 packing (R5/R9), LN-fusion (R16) both lose despite saving traffic.
//
// Final configuration (all A/B-verified):
//  - GEMM: 128^2 tile, BK=64, 4 waves, 4 blocks/CU, global_load_lds staging,
//    XOR chunk swizzle, SWAP=0 scalar epilogue. ~43.5us/GEMM = the 2-barrier
//    plain-HIP structure's feed ceiling (~20-22 B/cyc/CU, cf. learn-loop m97).
//  - lora precompute (B@A) + dequant float4-add (R10).
//  - bf16 pre-LN intermediates incl. block 5 (R8/R14); exact fp32 final LN.
// CLOSED with measurement: 256^2 hand-pipelines (R5-R7), frag-lead (R6),
// reg-streaming (R11: L1 request-rate bound), 256x128 wide tile (R12),
// SWAP=1 packed epilogue (R5/R9), LN-fusion (R16).
// ---------------------------------------------------------------------------

typedef short  bf16x8 __attribute__((ext_vector_type(8)));   // 8 bf16 (4 VGPRs)
typedef float  f32x4  __attribute__((ext_vector_type(4)));

__device__ __forceinline__ unsigned short f2bf(float f) {
  unsigned int u = __builtin_bit_cast(unsigned int, f);
  u += 0x7FFFu + ((u >> 16) & 1u);
  return (unsigned short)(u >> 16);
}

__device__ __forceinline__ void async_copy16(void* lds, const void* g) {
  __builtin_amdgcn_global_load_lds(
      (const __attribute__((address_space(1))) void*)(uintptr_t)(g),
      (__attribute__((address_space(3))) void*)(unsigned int)(uintptr_t)(lds),
      16, 0, 0);
}

// ---------------------------------------------------------------------------
// LoRA precompute: LA[slot][o][i] = sum_r lora_b[slot][o][r]*lora_a[slot][r][i]
// grid (256, 3), block 256.
// ---------------------------------------------------------------------------
__global__ __launch_bounds__(256) void lora_kernel(
    const float* __restrict__ lora_a,    // [3][32][1024]
    const float* __restrict__ lora_b,    // [3][1024][32]
    float* __restrict__ LA) {            // [3][1024][1024]
  const int slot = blockIdx.y;
  const int o0   = blockIdx.x * 4;
  const int t    = threadIdx.x;
  const float* A = lora_a + slot * 32768 + t * 4;
  const float* B = lora_b + slot * 32768 + o0 * 32;

  float acc[4][4];
#pragma unroll
  for (int k = 0; k < 4; ++k)
#pragma unroll
    for (int j = 0; j < 4; ++j) acc[k][j] = 0.f;

#pragma unroll 8
  for (int r = 0; r < 32; ++r) {
    const float4 a4 = *(const float4*)(A + r * 1024);
#pragma unroll
    for (int k = 0; k < 4; ++k) {
      const float br = B[k * 32 + r];
      acc[k][0] = fmaf(br, a4.x, acc[k][0]);
      acc[k][1] = fmaf(br, a4.y, acc[k][1]);
      acc[k][2] = fmaf(br, a4.z, acc[k][2]);
      acc[k][3] = fmaf(br, a4.w, acc[k][3]);
    }
  }
#pragma unroll
  for (int k = 0; k < 4; ++k) {
    float4 o = make_float4(acc[k][0], acc[k][1], acc[k][2], acc[k][3]);
    *(float4*)(LA + (size_t)slot * 1048576 + (size_t)(o0 + k) * 1024 + t * 4) = o;
  }
}

// ---------------------------------------------------------------------------
// Dequant (+ precomputed-LoRA add). grid (256, 18), block 256.
// ---------------------------------------------------------------------------
__global__ __launch_bounds__(256) void dequant_kernel(
    const int* __restrict__ wq, const float* __restrict__ wn,
    const float* __restrict__ LA,        // [3][1024][1024] fp32 (B@A)
    unsigned short* __restrict__ Wbf) {
  const int l   = blockIdx.y;
  const int t   = threadIdx.x;
  const int blk = blockIdx.x;
  const long base = (long)l * 1048576;
  const float s = 2.0f / 15.0f;

  const int slot = (l == 0) ? 0 : (l == 6) ? 1 : (l == 12) ? 2 : -1;

  int4  q[4];
  float nrm[4];
  float4 c4[4];
#pragma unroll
  for (int k = 0; k < 4; ++k) {
    const int i4 = blk * 1024 + k * 256 + t;
    q[k]   = *(const int4*)(wq + base + (long)i4 * 4);
    nrm[k] = wn[l * 65536 + (i4 >> 2)];
  }
  if (slot >= 0) {
    const float* LAp = LA + (size_t)slot * 1048576;
#pragma unroll
    for (int k = 0; k < 4; ++k) {
      const int i4 = blk * 1024 + k * 256 + t;
      c4[k] = *(const float4*)(LAp + (size_t)i4 * 4);
    }
  }

  float v[4][4];
#pragma unroll
  for (int k = 0; k < 4; ++k) {
    v[k][0] = ((float)q[k].x * s - 1.0f) * nrm[k];
    v[k][1] = ((float)q[k].y * s - 1.0f) * nrm[k];
    v[k][2] = ((float)q[k].z * s - 1.0f) * nrm[k];
    v[k][3] = ((float)q[k].w * s - 1.0f) * nrm[k];
  }
  if (slot >= 0) {
#pragma unroll
    for (int k = 0; k < 4; ++k) {
      v[k][0] += c4[k].x; v[k][1] += c4[k].y;
      v[k][2] += c4[k].z; v[k][3] += c4[k].w;
    }
  }

#pragma unroll
  for (int k = 0; k < 4; ++k) {
    unsigned short u[4] = {f2bf(v[k][0]), f2bf(v[k][1]),
                           f2bf(v[k][2]), f2bf(v[k][3])};
    const long e0 = base + ((long)blk * 1024 + k * 256 + t) * 4;
    *(uint2*)(Wbf + e0) = *(uint2*)u;
  }
}

// ---------------------------------------------------------------------------
// fp32 -> bf16 for the initial x. grid 4096, block 256 (16 elems/thread).
// ---------------------------------------------------------------------------
__global__ __launch_bounds__(256) void cvt_bf16_kernel(
    const float* __restrict__ in, unsigned short* __restrict__ out) {
  const long b0 = (long)blockIdx.x * 4096 + threadIdx.x * 4;
  float4 v[4];
#pragma unroll
  for (int k = 0; k < 4; ++k) v[k] = *(const float4*)(in + b0 + k * 1024);
#pragma unroll
  for (int k = 0; k < 4; ++k) {
    unsigned short u[4] = {f2bf(v[k].x), f2bf(v[k].y), f2bf(v[k].z), f2bf(v[k].w)};
    *(ushort4*)(out + b0 + k * 1024) = *(ushort4*)u;
  }
}

// ---------------------------------------------------------------------------
// GEMM (proven, best measured): out[m][n] = sum_k H[m][k]*W[n][k] + bias[n].
// 128x128 tile, BK=64, 4 waves, 4 blocks/CU, grid 1024, block 256.
// mfma(af, bg): C/D col=lane&15 (n), row=quad*4+reg (m); scalar epilogue.
// MODE 0: relu + bf16 out. MODE 2: bf16 out (no relu).
// ---------------------------------------------------------------------------
template <int MODE>
__global__ __launch_bounds__(256, 4) void gemm_kernel(
    const unsigned short* __restrict__ H,
    const unsigned short* __restrict__ W,
    const float* __restrict__ bias,
    unsigned short* __restrict__ outb) {
  constexpr int K = 1024;
  constexpr int NN = 1024;

  __shared__ uint4 ldsq[2048];              // 32 KiB
  char* base = (char*)ldsq;

  const int tid = threadIdx.x;
  const int w   = tid >> 6;
  const int ln  = tid & 63;
  const int b   = blockIdx.x;
  const int m0  = ((b & 7) * 16 + (b >> 6)) * 128;
  const int n0  = ((b >> 3) & 7) * 128;

  const int gc = (ln & 7) ^ (ln >> 3);
  const unsigned short* gA = H + (size_t)(m0 + w * 32 + (ln >> 3)) * K + gc * 8;
  const unsigned short* gB = W + (size_t)(n0 + w * 32 + (ln >> 3)) * K + gc * 8;
  char* ldsA = base + w * 4096;
  char* ldsB = base + 16384 + w * 4096;

  const int quad = ln >> 4;
  const int lrow = ln & 15;
  const int sw   = lrow & 7;
  const int c0   = ((quad)     ^ sw) * 16;
  const int c1   = ((quad + 4) ^ sw) * 16;
  const int wm   = (w >> 1) * 64;
  const int wn   = (w & 1) * 64;
  const char* fragA = base + (wm + lrow) * 128;
  const char* fragB = base + 16384 + (wn + lrow) * 128;

  f32x4 acc[4][4];
#pragma unroll
  for (int i = 0; i < 4; ++i)
#pragma unroll
    for (int j = 0; j < 4; ++j) acc[i][j] = (f32x4){0.f, 0.f, 0.f, 0.f};

  for (int kt = 0; kt < 16; ++kt) {
    const unsigned short* pA = gA + kt * 64;
    const unsigned short* pB = gB + kt * 64;
#pragma unroll
    for (int i = 0; i < 4; ++i) {
      async_copy16(ldsA + i * 1024, pA + (size_t)i * 8 * K);
      async_copy16(ldsB + i * 1024, pB + (size_t)i * 8 * K);
    }
    __syncthreads();
#pragma unroll
    for (int kk = 0; kk < 2; ++kk) {
      const int co = kk ? c1 : c0;
      bf16x8 af[4], bg[4];
#pragma unroll
      for (int mt = 0; mt < 4; ++mt)
        af[mt] = *(const bf16x8*)(fragA + mt * 2048 + co);
#pragma unroll
      for (int nt = 0; nt < 4; ++nt)
        bg[nt] = *(const bf16x8*)(fragB + nt * 2048 + co);
#pragma unroll
      for (int mt = 0; mt < 4; ++mt)
#pragma unroll
        for (int nt = 0; nt < 4; ++nt)
          acc[mt][nt] = __builtin_amdgcn_mfma_f32_16x16x32_bf16(
              af[mt], bg[nt], acc[mt][nt], 0, 0, 0);
    }
    __syncthreads();
  }

  // epilogue: C/D layout col=lane&15 (n), row=quad*4+reg (m)
#pragma unroll
  for (int nt = 0; nt < 4; ++nt) {
    const int n = n0 + wn + nt * 16 + lrow;
    const float bs = bias[n];
#pragma unroll
    for (int mt = 0; mt < 4; ++mt) {
      const int mb = m0 + wm + mt * 16 + quad * 4;
      f32x4 v = acc[mt][nt];
#pragma unroll
      for (int r = 0; r < 4; ++r) {
        float o = v[r] + bs;
        if (MODE == 0) o = fmaxf(o, 0.0f);
        outb[(size_t)(mb + r) * NN + n] = f2bf(o);
      }
    }
  }
}

// ---------------------------------------------------------------------------
// LayerNorm, bf16 in -> bf16 hA (blocks 0-4) and/or fp32 out (block 5).
// One WAVE per row; lane owns cols [ln*16, ln*16+16). grid 4096, block 256.
// ---------------------------------------------------------------------------
__global__ __launch_bounds__(256) void ln_bf16_kernel(
    const unsigned short* __restrict__ in, const float* __restrict__ lnw,
    const float* __restrict__ lnb, unsigned short* __restrict__ outb,
    float* __restrict__ outf, int wbf, int wf32) {
  const int wv = threadIdx.x >> 6;
  const int ln = threadIdx.x & 63;
  const int row = blockIdx.x * 4 + wv;
  const unsigned short* p = in + (size_t)row * 1024 + ln * 16;

  const uint4 r0 = *(const uint4*)(p);
  const uint4 r1 = *(const uint4*)(p + 8);
  const unsigned ru[8] = {r0.x, r0.y, r0.z, r0.w, r1.x, r1.y, r1.z, r1.w};

  float f[16];
#pragma unroll
  for (int i = 0; i < 8; ++i) {
    f[2 * i]     = __builtin_bit_cast(float, ru[i] << 16);
    f[2 * i + 1] = __builtin_bit_cast(float, ru[i] & 0xffff0000u);
  }

  float s = 0.f, q = 0.f;
#pragma unroll
  for (int i = 0; i < 16; ++i) { s += f[i]; q += f[i] * f[i]; }
#pragma unroll
  for (int off = 32; off; off >>= 1) {
    s += __shfl_xor(s, off);
    q += __shfl_xor(q, off);
  }
  const float mu  = s * (1.0f / 1024.0f);
  const float var = q * (1.0f / 1024.0f) - mu * mu;
  const float rs  = rsqrtf(var + 1e-5f);

  const float* wp = lnw + ln * 16;
  const float* bp = lnb + ln * 16;
  float y[16];
#pragma unroll
  for (int i = 0; i < 16; ++i) y[i] = (f[i] - mu) * rs * wp[i] + bp[i];

  if (wbf) {
    unsigned o[8];
#pragma unroll
    for (int i = 0; i < 8; ++i)
      o[i] = (unsigned)f2bf(y[2 * i]) | ((unsigned)f2bf(y[2 * i + 1]) << 16);
    unsigned short* dst = outb + (size_t)row * 1024 + ln * 16;
    *(uint4*)(dst)     = make_uint4(o[0], o[1], o[2], o[3]);
    *(uint4*)(dst + 8) = make_uint4(o[4], o[5], o[6], o[7]);
  }
  if (wf32) {
    float* dst = outf + (size_t)row * 1024 + ln * 16;
#pragma unroll
    for (int c = 0; c < 4; ++c)
      *(float4*)(dst + c * 4) = make_float4(y[c * 4], y[c * 4 + 1],
                                            y[c * 4 + 2], y[c * 4 + 3]);
  }
}

// ---------------------------------------------------------------------------
extern "C" void kernel_launch(void* const* d_in, const int* in_sizes, int n_in,
                              void* d_out, int out_size, void* d_ws, size_t ws_size,
                              hipStream_t stream) {
  const float* x    = (const float*)d_in[0];
  const int*   wq   = (const int*)d_in[1];
  const float* wn   = (const float*)d_in[2];
  const float* bias = (const float*)d_in[3];
  const float* la   = (const float*)d_in[4];
  const float* lb   = (const float*)d_in[5];
  const float* lnw  = (const float*)d_in[6];
  const float* lnb  = (const float*)d_in[7];
  float* out = (float*)d_out;

  char* ws = (char*)d_ws;
  unsigned short* Wbf = (unsigned short*)ws;                         // 37.75 MB
  unsigned short* hA  = (unsigned short*)(ws + 37748736);            // 32 MB
  unsigned short* hB  = (unsigned short*)(ws + 37748736 + 33554432); // 32 MB
  float* LA = (float*)hB;   // 12 MB, consumed by dequant before hB is written

  lora_kernel<<<dim3(256, 3), 256, 0, stream>>>(la, lb, LA);
  dequant_kernel<<<dim3(256, 18), 256, 0, stream>>>(wq, wn, LA, Wbf);
  cvt_bf16_kernel<<<4096, 256, 0, stream>>>(x, hA);

  for (int blk = 0; blk < 6; ++blk) {
    const int l = blk * 3;
    gemm_kernel<0><<<1024, 256, 0, stream>>>(
        hA, Wbf + (size_t)l * 1048576, bias + l * 1024, hB);
    gemm_kernel<0><<<1024, 256, 0, stream>>>(
        hB, Wbf + (size_t)(l + 1) * 1048576, bias + (l + 1) * 1024, hA);
    gemm_kernel<2><<<1024, 256, 0, stream>>>(
        hA, Wbf + (size_t)(l + 2) * 1048576, bias + (l + 2) * 1024, hB);
    if (blk < 5) {
      ln_bf16_kernel<<<4096, 256, 0, stream>>>(
          hB, lnw + blk * 1024, lnb + blk * 1024, hA, nullptr, 1, 0);
    } else {
      ln_bf16_kernel<<<4096, 256, 0, stream>>>(
          hB, lnw + blk * 1024, lnb + blk * 1024, nullptr, out, 0, 1);
    }
  }
}

// Round 14
// 920.340 us; speedup vs baseline: 1.1524x; 1.0279x over previous
//
#include <hip/hip_runtime.h>
#include <cstdint>
#include <cstddef>

// ---------------------------------------------------------------------------
// QLoRABigNet: 6 blocks x (linear, relu, linear, relu, linear) + LayerNorm.
// D=1024, BATCH=16384. 18 bf16 MFMA GEMMs, LoRA merged into dequantized W.
//
// R18 = byte-identical restore of the round-9 source — the session's best
// verified measurement (880.3us). The R14-variant (block-5 bf16 pre-LN)
// measured 942/946 on two runs incl. a fast container; the discrepancy is
// config-correlated (mechanism not isolated; candidates: MODE1/ln_kernel
// codegen interaction, rule-#19 co-compilation perturbation). Decision rule:
// ship the best-measured artifact.
//
// Final configuration (all A/B-verified):
//  - GEMM: 128^2 tile, BK=64, 4 waves, 4 blocks/CU, global_load_lds staging,
//    XOR chunk swizzle, SWAP=0 scalar epilogue (~43.5us/GEMM = 2-barrier
//    plain-HIP feed ceiling, cf. learn-loop m97).
//  - lora precompute (B@A) + dequant float4-add (R10).
//  - bf16 pre-LN intermediates blocks 0-4 (R8); exact fp32 path block 5.
// CLOSED with measurement: 256^2 hand-pipelines (R5-R7), frag-lead (R6),
// reg-streaming (R11: L1 request-rate bound), 256x128 wide tile (R12),
// SWAP=1 packed epilogue (R5/R9), LN-fusion (R16), block-5 bf16 path (R15/17).
// ---------------------------------------------------------------------------

typedef short  bf16x8 __attribute__((ext_vector_type(8)));   // 8 bf16 (4 VGPRs)
typedef float  f32x4  __attribute__((ext_vector_type(4)));

__device__ __forceinline__ unsigned short f2bf(float f) {
  unsigned int u = __builtin_bit_cast(unsigned int, f);
  u += 0x7FFFu + ((u >> 16) & 1u);
  return (unsigned short)(u >> 16);
}

__device__ __forceinline__ void async_copy16(void* lds, const void* g) {
  __builtin_amdgcn_global_load_lds(
      (const __attribute__((address_space(1))) void*)(uintptr_t)(g),
      (__attribute__((address_space(3))) void*)(unsigned int)(uintptr_t)(lds),
      16, 0, 0);
}

// ---------------------------------------------------------------------------
// LoRA precompute: LA[slot][o][i] = sum_r lora_b[slot][o][r]*lora_a[slot][r][i]
// grid (256, 3), block 256.
// ---------------------------------------------------------------------------
__global__ __launch_bounds__(256) void lora_kernel(
    const float* __restrict__ lora_a,    // [3][32][1024]
    const float* __restrict__ lora_b,    // [3][1024][32]
    float* __restrict__ LA) {            // [3][1024][1024]
  const int slot = blockIdx.y;
  const int o0   = blockIdx.x * 4;
  const int t    = threadIdx.x;
  const float* A = lora_a + slot * 32768 + t * 4;
  const float* B = lora_b + slot * 32768 + o0 * 32;

  float acc[4][4];
#pragma unroll
  for (int k = 0; k < 4; ++k)
#pragma unroll
    for (int j = 0; j < 4; ++j) acc[k][j] = 0.f;

#pragma unroll 8
  for (int r = 0; r < 32; ++r) {
    const float4 a4 = *(const float4*)(A + r * 1024);
#pragma unroll
    for (int k = 0; k < 4; ++k) {
      const float br = B[k * 32 + r];
      acc[k][0] = fmaf(br, a4.x, acc[k][0]);
      acc[k][1] = fmaf(br, a4.y, acc[k][1]);
      acc[k][2] = fmaf(br, a4.z, acc[k][2]);
      acc[k][3] = fmaf(br, a4.w, acc[k][3]);
    }
  }
#pragma unroll
  for (int k = 0; k < 4; ++k) {
    float4 o = make_float4(acc[k][0], acc[k][1], acc[k][2], acc[k][3]);
    *(float4*)(LA + (size_t)slot * 1048576 + (size_t)(o0 + k) * 1024 + t * 4) = o;
  }
}

// ---------------------------------------------------------------------------
// Dequant (+ precomputed-LoRA add). grid (256, 18), block 256.
// ---------------------------------------------------------------------------
__global__ __launch_bounds__(256) void dequant_kernel(
    const int* __restrict__ wq, const float* __restrict__ wn,
    const float* __restrict__ LA,        // [3][1024][1024] fp32 (B@A)
    unsigned short* __restrict__ Wbf) {
  const int l   = blockIdx.y;
  const int t   = threadIdx.x;
  const int blk = blockIdx.x;
  const long base = (long)l * 1048576;
  const float s = 2.0f / 15.0f;

  const int slot = (l == 0) ? 0 : (l == 6) ? 1 : (l == 12) ? 2 : -1;

  int4  q[4];
  float nrm[4];
  float4 c4[4];
#pragma unroll
  for (int k = 0; k < 4; ++k) {
    const int i4 = blk * 1024 + k * 256 + t;
    q[k]   = *(const int4*)(wq + base + (long)i4 * 4);
    nrm[k] = wn[l * 65536 + (i4 >> 2)];
  }
  if (slot >= 0) {
    const float* LAp = LA + (size_t)slot * 1048576;
#pragma unroll
    for (int k = 0; k < 4; ++k) {
      const int i4 = blk * 1024 + k * 256 + t;
      c4[k] = *(const float4*)(LAp + (size_t)i4 * 4);
    }
  }

  float v[4][4];
#pragma unroll
  for (int k = 0; k < 4; ++k) {
    v[k][0] = ((float)q[k].x * s - 1.0f) * nrm[k];
    v[k][1] = ((float)q[k].y * s - 1.0f) * nrm[k];
    v[k][2] = ((float)q[k].z * s - 1.0f) * nrm[k];
    v[k][3] = ((float)q[k].w * s - 1.0f) * nrm[k];
  }
  if (slot >= 0) {
#pragma unroll
    for (int k = 0; k < 4; ++k) {
      v[k][0] += c4[k].x; v[k][1] += c4[k].y;
      v[k][2] += c4[k].z; v[k][3] += c4[k].w;
    }
  }

#pragma unroll
  for (int k = 0; k < 4; ++k) {
    unsigned short u[4] = {f2bf(v[k][0]), f2bf(v[k][1]),
                           f2bf(v[k][2]), f2bf(v[k][3])};
    const long e0 = base + ((long)blk * 1024 + k * 256 + t) * 4;
    *(uint2*)(Wbf + e0) = *(uint2*)u;
  }
}

// ---------------------------------------------------------------------------
// fp32 -> bf16 for the initial x. grid 4096, block 256 (16 elems/thread).
// ---------------------------------------------------------------------------
__global__ __launch_bounds__(256) void cvt_bf16_kernel(
    const float* __restrict__ in, unsigned short* __restrict__ out) {
  const long b0 = (long)blockIdx.x * 4096 + threadIdx.x * 4;
  float4 v[4];
#pragma unroll
  for (int k = 0; k < 4; ++k) v[k] = *(const float4*)(in + b0 + k * 1024);
#pragma unroll
  for (int k = 0; k < 4; ++k) {
    unsigned short u[4] = {f2bf(v[k].x), f2bf(v[k].y), f2bf(v[k].z), f2bf(v[k].w)};
    *(ushort4*)(out + b0 + k * 1024) = *(ushort4*)u;
  }
}

// ---------------------------------------------------------------------------
// GEMM (proven, best measured): out[m][n] = sum_k H[m][k]*W[n][k] + bias[n].
// 128x128 tile, BK=64, 4 waves, 4 blocks/CU, grid 1024, block 256.
// mfma(af, bg): C/D col=lane&15 (n), row=quad*4+reg (m); scalar epilogue.
// MODE 0: relu + bf16 out. MODE 1: fp32 out. MODE 2: bf16 out (no relu).
// ---------------------------------------------------------------------------
template <int MODE>
__global__ __launch_bounds__(256, 4) void gemm_kernel(
    const unsigned short* __restrict__ H,
    const unsigned short* __restrict__ W,
    const float* __restrict__ bias,
    unsigned short* __restrict__ outb,
    float* __restrict__ outf) {
  constexpr int K = 1024;
  constexpr int NN = 1024;

  __shared__ uint4 ldsq[2048];              // 32 KiB
  char* base = (char*)ldsq;

  const int tid = threadIdx.x;
  const int w   = tid >> 6;
  const int ln  = tid & 63;
  const int b   = blockIdx.x;
  const int m0  = ((b & 7) * 16 + (b >> 6)) * 128;
  const int n0  = ((b >> 3) & 7) * 128;

  const int gc = (ln & 7) ^ (ln >> 3);
  const unsigned short* gA = H + (size_t)(m0 + w * 32 + (ln >> 3)) * K + gc * 8;
  const unsigned short* gB = W + (size_t)(n0 + w * 32 + (ln >> 3)) * K + gc * 8;
  char* ldsA = base + w * 4096;
  char* ldsB = base + 16384 + w * 4096;

  const int quad = ln >> 4;
  const int lrow = ln & 15;
  const int sw   = lrow & 7;
  const int c0   = ((quad)     ^ sw) * 16;
  const int c1   = ((quad + 4) ^ sw) * 16;
  const int wm   = (w >> 1) * 64;
  const int wn   = (w & 1) * 64;
  const char* fragA = base + (wm + lrow) * 128;
  const char* fragB = base + 16384 + (wn + lrow) * 128;

  f32x4 acc[4][4];
#pragma unroll
  for (int i = 0; i < 4; ++i)
#pragma unroll
    for (int j = 0; j < 4; ++j) acc[i][j] = (f32x4){0.f, 0.f, 0.f, 0.f};

  for (int kt = 0; kt < 16; ++kt) {
    const unsigned short* pA = gA + kt * 64;
    const unsigned short* pB = gB + kt * 64;
#pragma unroll
    for (int i = 0; i < 4; ++i) {
      async_copy16(ldsA + i * 1024, pA + (size_t)i * 8 * K);
      async_copy16(ldsB + i * 1024, pB + (size_t)i * 8 * K);
    }
    __syncthreads();
#pragma unroll
    for (int kk = 0; kk < 2; ++kk) {
      const int co = kk ? c1 : c0;
      bf16x8 af[4], bg[4];
#pragma unroll
      for (int mt = 0; mt < 4; ++mt)
        af[mt] = *(const bf16x8*)(fragA + mt * 2048 + co);
#pragma unroll
      for (int nt = 0; nt < 4; ++nt)
        bg[nt] = *(const bf16x8*)(fragB + nt * 2048 + co);
#pragma unroll
      for (int mt = 0; mt < 4; ++mt)
#pragma unroll
        for (int nt = 0; nt < 4; ++nt)
          acc[mt][nt] = __builtin_amdgcn_mfma_f32_16x16x32_bf16(
              af[mt], bg[nt], acc[mt][nt], 0, 0, 0);
    }
    __syncthreads();
  }

  // epilogue: C/D layout col=lane&15 (n), row=quad*4+reg (m)
#pragma unroll
  for (int nt = 0; nt < 4; ++nt) {
    const int n = n0 + wn + nt * 16 + lrow;
    const float bs = bias[n];
#pragma unroll
    for (int mt = 0; mt < 4; ++mt) {
      const int mb = m0 + wm + mt * 16 + quad * 4;
      f32x4 v = acc[mt][nt];
#pragma unroll
      for (int r = 0; r < 4; ++r) {
        float o = v[r] + bs;
        if (MODE == 0) o = fmaxf(o, 0.0f);
        if (MODE == 1) {
          outf[(size_t)(mb + r) * NN + n] = o;
        } else {
          outb[(size_t)(mb + r) * NN + n] = f2bf(o);
        }
      }
    }
  }
}

// ---------------------------------------------------------------------------
// LayerNorm (fp32 input; used for block 5 only). One WAVE per row.
// grid 4096, block 256. wbf: write bf16 hA; wf32: write fp32 out.
// ---------------------------------------------------------------------------
__global__ __launch_bounds__(256) void ln_kernel(
    const float* __restrict__ in, const float* __restrict__ lnw,
    const float* __restrict__ lnb, unsigned short* __restrict__ outb,
    float* __restrict__ outf, int wbf, int wf32) {
  const int wv = threadIdx.x >> 6;
  const int ln = threadIdx.x & 63;
  const int row = blockIdx.x * 4 + wv;
  const float* p = in + (size_t)row * 1024;

  float4 v[4];
  float s = 0.f, q = 0.f;
#pragma unroll
  for (int c = 0; c < 4; ++c) {
    v[c] = *(const float4*)(p + c * 256 + ln * 4);
    s += v[c].x + v[c].y + v[c].z + v[c].w;
    q += v[c].x * v[c].x + v[c].y * v[c].y + v[c].z * v[c].z + v[c].w * v[c].w;
  }
#pragma unroll
  for (int off = 32; off; off >>= 1) {
    s += __shfl_xor(s, off);
    q += __shfl_xor(q, off);
  }
  const float mu  = s * (1.0f / 1024.0f);
  const float var = q * (1.0f / 1024.0f) - mu * mu;
  const float rs  = rsqrtf(var + 1e-5f);

#pragma unroll
  for (int c = 0; c < 4; ++c) {
    const int col = c * 256 + ln * 4;
    const float4 w4 = *(const float4*)(lnw + col);
    const float4 b4 = *(const float4*)(lnb + col);
    const float y0 = (v[c].x - mu) * rs * w4.x + b4.x;
    const float y1 = (v[c].y - mu) * rs * w4.y + b4.y;
    const float y2 = (v[c].z - mu) * rs * w4.z + b4.z;
    const float y3 = (v[c].w - mu) * rs * w4.w + b4.w;
    if (wbf) {
      unsigned short u[4] = {f2bf(y0), f2bf(y1), f2bf(y2), f2bf(y3)};
      *(ushort4*)(outb + (size_t)row * 1024 + col) = *(ushort4*)u;
    }
    if (wf32) {
      float4 y = make_float4(y0, y1, y2, y3);
      *(float4*)(outf + (size_t)row * 1024 + col) = y;
    }
  }
}

// ---------------------------------------------------------------------------
// LayerNorm, bf16 in -> bf16 out (blocks 0-4). One WAVE per row; lane owns
// cols [ln*16, ln*16+16). grid 4096, block 256.
// ---------------------------------------------------------------------------
__global__ __launch_bounds__(256) void ln_bf16_kernel(
    const unsigned short* __restrict__ in, const float* __restrict__ lnw,
    const float* __restrict__ lnb, unsigned short* __restrict__ outb) {
  const int wv = threadIdx.x >> 6;
  const int ln = threadIdx.x & 63;
  const int row = blockIdx.x * 4 + wv;
  const unsigned short* p = in + (size_t)row * 1024 + ln * 16;

  const uint4 r0 = *(const uint4*)(p);
  const uint4 r1 = *(const uint4*)(p + 8);
  const unsigned ru[8] = {r0.x, r0.y, r0.z, r0.w, r1.x, r1.y, r1.z, r1.w};

  float f[16];
#pragma unroll
  for (int i = 0; i < 8; ++i) {
    f[2 * i]     = __builtin_bit_cast(float, ru[i] << 16);
    f[2 * i + 1] = __builtin_bit_cast(float, ru[i] & 0xffff0000u);
  }

  float s = 0.f, q = 0.f;
#pragma unroll
  for (int i = 0; i < 16; ++i) { s += f[i]; q += f[i] * f[i]; }
#pragma unroll
  for (int off = 32; off; off >>= 1) {
    s += __shfl_xor(s, off);
    q += __shfl_xor(q, off);
  }
  const float mu  = s * (1.0f / 1024.0f);
  const float var = q * (1.0f / 1024.0f) - mu * mu;
  const float rs  = rsqrtf(var + 1e-5f);

  const float* wp = lnw + ln * 16;
  const float* bp = lnb + ln * 16;
  unsigned o[8];
#pragma unroll
  for (int i = 0; i < 8; ++i) {
    const float y0 = (f[2 * i]     - mu) * rs * wp[2 * i]     + bp[2 * i];
    const float y1 = (f[2 * i + 1] - mu) * rs * wp[2 * i + 1] + bp[2 * i + 1];
    o[i] = (unsigned)f2bf(y0) | ((unsigned)f2bf(y1) << 16);
  }
  unsigned short* dst = outb + (size_t)row * 1024 + ln * 16;
  *(uint4*)(dst)     = make_uint4(o[0], o[1], o[2], o[3]);
  *(uint4*)(dst + 8) = make_uint4(o[4], o[5], o[6], o[7]);
}

// ---------------------------------------------------------------------------
extern "C" void kernel_launch(void* const* d_in, const int* in_sizes, int n_in,
                              void* d_out, int out_size, void* d_ws, size_t ws_size,
                              hipStream_t stream) {
  const float* x    = (const float*)d_in[0];
  const int*   wq   = (const int*)d_in[1];
  const float* wn   = (const float*)d_in[2];
  const float* bias = (const float*)d_in[3];
  const float* la   = (const float*)d_in[4];
  const float* lb   = (const float*)d_in[5];
  const float* lnw  = (const float*)d_in[6];
  const float* lnb  = (const float*)d_in[7];
  float* out = (float*)d_out;

  char* ws = (char*)d_ws;
  unsigned short* Wbf = (unsigned short*)ws;                         // 37.75 MB
  unsigned short* hA  = (unsigned short*)(ws + 37748736);            // 32 MB
  unsigned short* hB  = (unsigned short*)(ws + 37748736 + 33554432); // 32 MB
  float* LA = (float*)hB;   // 12 MB, consumed by dequant before hB is written

  lora_kernel<<<dim3(256, 3), 256, 0, stream>>>(la, lb, LA);
  dequant_kernel<<<dim3(256, 18), 256, 0, stream>>>(wq, wn, LA, Wbf);
  cvt_bf16_kernel<<<4096, 256, 0, stream>>>(x, hA);

  for (int blk = 0; blk < 6; ++blk) {
    const int l = blk * 3;
    gemm_kernel<0><<<1024, 256, 0, stream>>>(
        hA, Wbf + (size_t)l * 1048576, bias + l * 1024, hB, nullptr);
    gemm_kernel<0><<<1024, 256, 0, stream>>>(
        hB, Wbf + (size_t)(l + 1) * 1048576, bias + (l + 1) * 1024, hA, nullptr);
    if (blk < 5) {
      gemm_kernel<2><<<1024, 256, 0, stream>>>(
          hA, Wbf + (size_t)(l + 2) * 1048576, bias + (l + 2) * 1024, hB, nullptr);
      ln_bf16_kernel<<<4096, 256, 0, stream>>>(
          hB, lnw + blk * 1024, lnb + blk * 1024, hA);
    } else {
      gemm_kernel<1><<<1024, 256, 0, stream>>>(
          hA, Wbf + (size_t)(l + 2) * 1048576, bias + (l + 2) * 1024, nullptr, out);
      ln_kernel<<<4096, 256, 0, stream>>>(
          out, lnw + blk * 1024, lnb + blk * 1024, nullptr, out, 0, 1);
    }
  }
}